// Round 4
// baseline (554.947 us; speedup 1.0000x reference)
//
#include <hip/hip_runtime.h>

// SGM min-sum message passing, 4 directions, dense 21x21 label context.
// out = sum_d L_d - 3u.
//
// Path A (ws >= 4*NELEM floats exactly):
//   transpose2: uT[b][s][w][h] from u (84 planes) AND ewT planes for dirs
//     2,3 OVERLAID into l2t/l3t plane (b*21+20) -- no extra workspace.
//     (Race-free: task (b,p,dir) is sole reader+writer of those rows, and
//     reads complete (waitcnt) before its own flush writes them.)
//   sweep4: 8192 tasks (4 dirs x 2048 lines), 21 lanes/task, 3 tasks/wave.
//     ALL streams stride-1, consumed in 16-step blocks with a 4-slot
//     rotating register pipeline (u and w): 3 blocks (384 B/lane) in
//     flight during every PROCESS. R3 analysis: read BW was Little's-law
//     capped at 1.55 TB/s with only 128 B in flight/wave; 3x in-flight
//     targets ~4 TB/s. Per-step all-to-all of 21 L values via padded LDS
//     row (wave-synchronous). Stores staged in LDS 32-step windows,
//     flushed as full 128-B-line wave stores (WRITE exact 352 MB).
//       dir0 -> out (raw L); dir1 -> l1 (L-u); dir2/3 -> l2t/l3t (L-u,
//       transposed planes), all label-major.
//   finish: out += l1 + T(l2t) + T(l3t) via 32x33 LDS tiles.
// Path B fallback (small ws): sequential no-scratch kernels (unchanged).

#define DLBL 21
#define SP 512
#define NB 4
#define SPSP ((long)SP * SP)
#define NELEM ((long)NB * DLBL * SP * SP)   // 22,020,096 floats

// ---- transpose: u planes (0..83) + ewT overlay planes (84..91) ----
__global__ __launch_bounds__(256)
void transpose2_kernel(const float* __restrict__ u, const float* __restrict__ ew,
                       float* __restrict__ uT, float* l2t, float* l3t)
{
    __shared__ float tile[32][33];
    const int plane = blockIdx.z;
    const float* src;
    float* dst;
    if (plane < NB * DLBL) {
        src = u  + (long)plane * SPSP;
        dst = uT + (long)plane * SPSP;
    } else {
        const int q = plane - NB * DLBL;            // q = b*2 + (dir-2)
        const int b = q >> 1, db = q & 1;
        src = ew + (long)(b * 4 + 2 + db) * SPSP;
        dst = (db ? l3t : l2t) + (long)(b * DLBL + 20) * SPSP;  // overlay
    }
    const int x0 = blockIdx.x * 32, y0 = blockIdx.y * 32;
    const int tx = threadIdx.x & 31, ty = threadIdx.x >> 5;  // 32 x 8
#pragma unroll
    for (int j = 0; j < 4; ++j)
        tile[ty + 8 * j][tx] = src[(long)(y0 + ty + 8 * j) * SP + (x0 + tx)];
    __syncthreads();
#pragma unroll
    for (int j = 0; j < 4; ++j)
        dst[(long)(x0 + ty + 8 * j) * SP + (y0 + tx)] = tile[tx][ty + 8 * j];
}

// ---------------- main sweep (Path A, 4-slot deep pipeline) ----------------
__global__ __launch_bounds__(64, 3)
void sweep4(const float* __restrict__ unary, const float* __restrict__ ew,
            const float* __restrict__ Vmat, const float* __restrict__ uT,
            float* __restrict__ out, float* __restrict__ l1,
            float* l2t, float* l3t)
{
    __shared__ float xch[4][24];
    __shared__ float stage[4][693];      // [group][s*33 + (t&31)], +1 pad/row
    const int lane = threadIdx.x;
    const int g    = lane / DLBL;              // 0..2 (3 = idle lane 63)
    const int s    = lane - g * DLBL;
    int taskId = blockIdx.x * 3 + (g < 3 ? g : 0);
    if (taskId >= 8192) taskId = 8191;

    const int dir  = taskId >> 11;
    const int line = taskId & 2047;
    const int b    = line >> 9;
    const int p    = line & (SP - 1);          // h for axis 0, w for axis 1
    const int axis = dir >> 1;
    const int rev  = dir & 1;
    const float usub = (dir == 0) ? 0.0f : 1.0f;   // dirs 1-3 store L-u

    float Vc[DLBL];
#pragma unroll
    for (int j = 0; j < DLBL; ++j) Vc[j] = Vmat[j * DLBL + s];

    const float4* ub4 = (const float4*)((axis ? uT : unary)
                        + (long)(b * DLBL + s) * SPSP + (long)p * SP);
    // w stream: stride-1 everywhere (ewT overlay planes for vertical dirs)
    const float* wbase = axis
        ? ((dir == 2 ? l2t : l3t) + (long)(b * DLBL + 20) * SPSP + (long)p * SP)
        : (ew + (long)(b * 4 + dir) * SPSP + (long)p * SP);
    const float4* wb4 = (const float4*)wbase;

    const int frow = lane >> 5, fcol = lane & 31;
    const int stbase = s * 33;

    // flush per-task constants, hoisted out of the loop
    float* fb[3]; int wrev[3]; bool fvalid[3];
#pragma unroll
    for (int gg = 0; gg < 3; ++gg) {
        const int tid = blockIdx.x * 3 + gg;
        fvalid[gg] = (tid < 8192);
        const int tid2 = fvalid[gg] ? tid : 8191;
        const int d_ = tid2 >> 11;
        const int ln = tid2 & 2047;
        const int bb = ln >> 9;
        const int pp = ln & (SP - 1);
        wrev[gg] = d_ & 1;
        float* dst = (d_ == 0) ? out : (d_ == 1) ? l1 : (d_ == 2) ? l2t : l3t;
        fb[gg] = dst + (long)(bb * DLBL) * SPSP + (long)pp * SP + (long)frow * SPSP;
    }

    float4 uS0[4], uS1[4], uS2[4], uS3[4];
    float4 wS0[4], wS1[4], wS2[4], wS3[4];
    float cur = 0.0f;

#define QIDX(bi, k) (rev ? (127 - 4 * (bi) - (k)) : (4 * (bi) + (k)))

#define LOADU(bi, U) do {                                                   \
    _Pragma("unroll")                                                       \
    for (int k = 0; k < 4; ++k) U[k] = ub4[QIDX(bi, k)];                    \
    } while (0)

#define LOADW(bi, W) do {                                                   \
    _Pragma("unroll")                                                       \
    for (int k = 0; k < 4; ++k) W[k] = wb4[QIDX(bi, k)];                    \
    } while (0)

#define PROC(bi, U, W, FIRSTB) do {                                         \
    _Pragma("unroll")                                                       \
    for (int k = 0; k < 4; ++k) {                                           \
        const float ua_[4] = {U[k].x, U[k].y, U[k].z, U[k].w};              \
        const float wa_[4] = {W[k].x, W[k].y, W[k].z, W[k].w};              \
        const int q_ = QIDX(bi, k);                                         \
        _Pragma("unroll")                                                   \
        for (int j = 0; j < 4; ++j) {                                       \
            const int   jc  = rev ? 3 - j : j;                              \
            const float u_c = ua_[jc];                                      \
            const float w_c = wa_[jc];                                      \
            const int   t   = q_ * 4 + jc;                                  \
            xch[g][s] = cur;                                                \
            __builtin_amdgcn_wave_barrier();                                \
            float Lp[24];                                                   \
            _Pragma("unroll")                                               \
            for (int qq = 0; qq < 6; ++qq)                                  \
                ((float4*)Lp)[qq] = ((const float4*)(&xch[g][0]))[qq];      \
            __builtin_amdgcn_wave_barrier();                                \
            float c[DLBL];                                                  \
            _Pragma("unroll")                                               \
            for (int jj = 0; jj < DLBL; ++jj)                               \
                c[jj] = fmaf(w_c, Vc[jj], Lp[jj]);                          \
            float m7[7];                                                    \
            _Pragma("unroll")                                               \
            for (int kk = 0; kk < 7; ++kk)                                  \
                m7[kk] = fminf(fminf(c[3*kk], c[3*kk+1]), c[3*kk+2]);       \
            const float ma = fminf(fminf(m7[0], m7[1]), m7[2]);             \
            const float mb = fminf(fminf(m7[3], m7[4]), m7[5]);             \
            const float nv = u_c + fminf(fminf(ma, mb), m7[6]);             \
            cur = ((FIRSTB) && k == 0 && j == 0) ? u_c : nv;                \
            stage[g][stbase + (t & 31)] = fmaf(-usub, u_c, cur);            \
        }                                                                   \
    } } while (0)

#define FLW(w_) do {                                                        \
    __builtin_amdgcn_wave_barrier();                                        \
    _Pragma("unroll")                                                       \
    for (int gg = 0; gg < 3; ++gg) {                                        \
        if (fvalid[gg]) {                                                   \
            float* bp = fb[gg] + (wrev[gg] ? (480 - 32 * (w_))              \
                                           : (32 * (w_)));                  \
            _Pragma("unroll")                                               \
            for (int r2 = 0; r2 < 11; ++r2) {                               \
                const int rr = 2 * r2 + frow;                               \
                if (rr < DLBL) bp[fcol] = stage[gg][rr * 33 + fcol];        \
                bp += 2 * SPSP;                                             \
            }                                                               \
        }                                                                   \
    }                                                                       \
    __builtin_amdgcn_wave_barrier();                                        \
} while (0)

    LOADU(0, uS0); LOADW(0, wS0);
    LOADU(1, uS1); LOADW(1, wS1);
    LOADU(2, uS2); LOADW(2, wS2);
    LOADU(3, uS3); LOADW(3, wS3);

    for (int ww = 0; ww < 8; ++ww) {
        const int B0 = 4 * ww;
        PROC(B0 + 0, uS0, wS0, (ww == 0));
        if (B0 + 4 < 32) { LOADU(B0 + 4, uS0); LOADW(B0 + 4, wS0); }
        PROC(B0 + 1, uS1, wS1, false);
        if (B0 + 5 < 32) { LOADU(B0 + 5, uS1); LOADW(B0 + 5, wS1); }
        FLW(2 * ww);
        PROC(B0 + 2, uS2, wS2, false);
        if (B0 + 6 < 32) { LOADU(B0 + 6, uS2); LOADW(B0 + 6, wS2); }
        PROC(B0 + 3, uS3, wS3, false);
        if (B0 + 7 < 32) { LOADU(B0 + 7, uS3); LOADW(B0 + 7, wS3); }
        FLW(2 * ww + 1);
    }

#undef QIDX
#undef LOADU
#undef LOADW
#undef PROC
#undef FLW
}

// ---------------- finish: out += l1 + T(l2t) + T(l3t) ----------------
__global__ __launch_bounds__(256)
void finish_kernel(const float* __restrict__ l1, const float* __restrict__ l2t,
                   const float* __restrict__ l3t, float* __restrict__ out)
{
    __shared__ float t2[32][33], t3[32][33];
    const long pb = (long)blockIdx.z * SPSP;
    const int x0 = blockIdx.x * 32, y0 = blockIdx.y * 32;
    const int tx = threadIdx.x & 31, ty = threadIdx.x >> 5;
#pragma unroll
    for (int j = 0; j < 4; ++j) {
        const long o = pb + (long)(x0 + ty + 8 * j) * SP + (y0 + tx);
        t2[ty + 8 * j][tx] = l2t[o];
        t3[ty + 8 * j][tx] = l3t[o];
    }
    __syncthreads();
#pragma unroll
    for (int j = 0; j < 4; ++j) {
        const long o = pb + (long)(y0 + ty + 8 * j) * SP + (x0 + tx);
        out[o] = out[o] + l1[o] + t2[tx][ty + 8 * j] + t3[tx][ty + 8 * j];
    }
}

// ---------------- fallback (Path B): no-scratch sequential sweeps ----------
template<int MODE>   // 1: dir0 store L to out; 2: out += L - u
__global__ __launch_bounds__(64)
void sweep_fb(const float* __restrict__ unary, const float* __restrict__ ew,
              const float* __restrict__ Vmat, float* __restrict__ out,
              int taskBase)
{
    __shared__ float xch[4][24];
    const int lane = threadIdx.x;
    const int g    = lane / DLBL;
    const int s    = lane - g * DLBL;
    int local = blockIdx.x * 3 + (g < 3 ? g : 0);
    const bool valid = (g < 3) && (local < 2048);
    if (local >= 2048) local = 2047;
    const int taskId = taskBase + local;
    const int dir  = taskId >> 11;
    const int line = taskId & 2047;
    const int b = line >> 9, p = line & (SP - 1);
    const int axis = dir >> 1, rev = dir & 1;

    float Vc[DLBL];
#pragma unroll
    for (int j = 0; j < DLBL; ++j) Vc[j] = Vmat[j * DLBL + s];

    const long ustep = axis ? SP : 1;
    const long ubase = (long)(b * DLBL + s) * SPSP + (axis ? (long)p : (long)p * SP);
    const long wbase = (long)(b * 4 + dir) * SPSP + (axis ? (long)p : (long)p * SP);
    const long uoff  = rev ? -ustep : ustep;
    const long ust   = rev ? (long)(SP - 1) * ustep : 0;

    const float* up = unary + ubase + ust;
    const float* wp = ew    + wbase + ust;
    float*       op = out   + ubase + ust;

    float cur = up[0];
    if (valid && MODE == 1) *op = cur;

    float ub0 = up[uoff], ub1 = up[2*uoff], ub2 = up[3*uoff], ub3 = up[4*uoff];
    float wb0 = wp[uoff], wb1 = wp[2*uoff], wb2 = wp[3*uoff], wb3 = wp[4*uoff];
    float ob0 = 0, ob1 = 0, ob2 = 0, ob3 = 0;
    if (MODE == 2) { ob0 = op[uoff]; ob1 = op[2*uoff]; ob2 = op[3*uoff]; ob3 = op[4*uoff]; }
    const float* upf = up + 4 * uoff;
    const float* wpf = wp + 4 * uoff;
    const float* opf = op + 4 * uoff;

    for (int t = 1; t < SP; ++t) {
        const float u_c = ub0, w_c = wb0, o_c = ob0;
        ub0 = ub1; ub1 = ub2; ub2 = ub3;
        wb0 = wb1; wb1 = wb2; wb2 = wb3;
        if (MODE == 2) { ob0 = ob1; ob1 = ob2; ob2 = ob3; }
        const bool adv = (t + 4) < SP;
        upf += adv ? uoff : 0; wpf += adv ? uoff : 0;
        ub3 = *upf; wb3 = *wpf;
        if (MODE == 2) { opf += adv ? uoff : 0; ob3 = *opf; }

        xch[g][s] = cur;
        __builtin_amdgcn_wave_barrier();
        float Lp[24];
#pragma unroll
        for (int q = 0; q < 6; ++q)
            ((float4*)Lp)[q] = ((const float4*)(&xch[g][0]))[q];
        __builtin_amdgcn_wave_barrier();

        float c[DLBL];
#pragma unroll
        for (int j = 0; j < DLBL; ++j) c[j] = fmaf(w_c, Vc[j], Lp[j]);
        float m7[7];
#pragma unroll
        for (int k = 0; k < 7; ++k)
            m7[k] = fminf(fminf(c[3*k], c[3*k+1]), c[3*k+2]);
        const float ma = fminf(fminf(m7[0], m7[1]), m7[2]);
        const float mb = fminf(fminf(m7[3], m7[4]), m7[5]);
        cur = u_c + fminf(fminf(ma, mb), m7[6]);

        op += uoff;
        if (valid) *op = (MODE == 2) ? (o_c + cur - u_c) : cur;
    }
}

extern "C" void kernel_launch(void* const* d_in, const int* in_sizes, int n_in,
                              void* d_out, int out_size, void* d_ws, size_t ws_size,
                              hipStream_t stream) {
    const float* unary = (const float*)d_in[0];   // (4,1,21,512,512) f32
    const float* ew    = (const float*)d_in[1];   // (4,4,512,512)   f32
    const float* Vmat  = (const float*)d_in[2];   // (21,21)         f32
    float* o = (float*)d_out;

    const size_t needA = (size_t)(4 * NELEM) * sizeof(float);   // 352,321,536 B

    if (ws_size >= needA) {
        float* uT  = (float*)d_ws;
        float* l1  = uT + NELEM;
        float* l2t = l1 + NELEM;
        float* l3t = l2t + NELEM;

        dim3 tg(16, 16, NB * DLBL + 8);           // +8 ewT overlay planes
        transpose2_kernel<<<tg, 256, 0, stream>>>(unary, ew, uT, l2t, l3t);

        const int grid = (8192 + 2) / 3;          // 2731
        sweep4<<<grid, 64, 0, stream>>>(unary, ew, Vmat, uT,
                                        o, l1, l2t, l3t);

        finish_kernel<<<dim3(16, 16, NB * DLBL), 256, 0, stream>>>(l1, l2t, l3t, o);
    } else {
        const int grid = (2048 + 2) / 3;          // 683
        sweep_fb<1><<<grid, 64, 0, stream>>>(unary, ew, Vmat, o, 0);
        for (int d = 1; d < 4; ++d)
            sweep_fb<2><<<grid, 64, 0, stream>>>(unary, ew, Vmat, o, d * 2048);
    }
}

// Round 5
// 477.469 us; speedup vs baseline: 1.1623x; 1.1623x over previous
//
#include <hip/hip_runtime.h>

// SGM min-sum message passing, 4 directions, dense 21x21 label context.
// out = sum_d L_d - 3u.
//
// Path A (ws >= 4*NELEM floats exactly):
//   transpose2: uT[b][s][w][h] from u (84 planes) AND ewT planes for dirs
//     2,3 OVERLAID into l2t/l3t plane (b*21+20) -- no extra workspace.
//     float4 loads + [32][36] LDS tile (16B-aligned float4 LDS writes).
//   sweep5: 8192 tasks, 21 lanes/task, 3 tasks/wave. Direction-PAIRED task
//     map: i<4096 -> (dir=i&1, line=i>>1); else (dir=2+(j&1), line=j>>1),
//     so fwd+bwd of one line share u/uT lines in L2 (kills the 2x u re-read
//     behind R3's 320MB FETCH). 4-slot rotating register pipeline with
//     BRANCHLESS CLAMPED prefetch (bi>31 -> 31; values unused, addresses
//     disjoint from pending flush lines incl. overlay rows) and
//     __launch_bounds__(64,2) (256-VGPR budget) -- fixes R4's scratch spill
//     (WRITE 570MB->must be exactly 344064 KB again).
//     Per-step all-to-all of 21 L values via padded LDS row (wave-sync).
//     Stores staged in LDS 32-step windows, flushed as full-line wave
//     stores: dir0->out (raw L), dir1->l1 (L-u), dir2/3->l2t/l3t (L-u,
//     transposed planes), all label-major.
//   finish: out += l1 + T(l2t) + T(l3t), float4 + [32][36] LDS tiles.
// Path B fallback (small ws): sequential no-scratch kernels (unchanged).

#define DLBL 21
#define SP 512
#define NB 4
#define SPSP ((long)SP * SP)
#define NELEM ((long)NB * DLBL * SP * SP)   // 22,020,096 floats

__device__ __forceinline__ void map_task(int i, int& dir, int& line)
{
    if (i < 4096) { dir = i & 1;       line = i >> 1; }
    else          { const int j = i - 4096; dir = 2 + (j & 1); line = j >> 1; }
}

// ---- transpose: u planes (0..83) + ewT overlay planes (84..91) ----
__global__ __launch_bounds__(256)
void transpose2_kernel(const float* __restrict__ u, const float* __restrict__ ew,
                       float* __restrict__ uT, float* l2t, float* l3t)
{
    __shared__ float tile[32][36];
    const int plane = blockIdx.z;
    const float* src;
    float* dst;
    if (plane < NB * DLBL) {
        src = u  + (long)plane * SPSP;
        dst = uT + (long)plane * SPSP;
    } else {
        const int q = plane - NB * DLBL;            // q = b*2 + (dir-2)
        const int b = q >> 1, db = q & 1;
        src = ew + (long)(b * 4 + 2 + db) * SPSP;
        dst = (db ? l3t : l2t) + (long)(b * DLBL + 20) * SPSP;  // overlay
    }
    const int x0 = blockIdx.x * 32, y0 = blockIdx.y * 32;
    const int r  = threadIdx.x >> 3;           // 0..31
    const int c4 = (threadIdx.x & 7) * 4;      // 0,4,..,28
    const float4 v = *(const float4*)&src[(long)(y0 + r) * SP + (x0 + c4)];
    *(float4*)&tile[r][c4] = v;
    __syncthreads();
    float4 ov;
    ov.x = tile[c4 + 0][r];
    ov.y = tile[c4 + 1][r];
    ov.z = tile[c4 + 2][r];
    ov.w = tile[c4 + 3][r];
    *(float4*)&dst[(long)(x0 + r) * SP + (y0 + c4)] = ov;
}

// ---------------- main sweep (Path A, 4-slot deep pipeline) ----------------
__global__ __launch_bounds__(64, 2)
void sweep5(const float* __restrict__ unary, const float* __restrict__ ew,
            const float* __restrict__ Vmat, const float* __restrict__ uT,
            float* __restrict__ out, float* __restrict__ l1,
            float* l2t, float* l3t)
{
    __shared__ float xch[4][24];
    __shared__ float stage[4][693];      // [group][s*33 + (t&31)], +1 pad/row
    const int lane = threadIdx.x;
    const int g    = lane / DLBL;              // 0..2 (3 = idle lane 63)
    const int s    = lane - g * DLBL;
    int taskId = blockIdx.x * 3 + (g < 3 ? g : 0);
    if (taskId >= 8192) taskId = 8191;

    int dir, line;
    map_task(taskId, dir, line);
    const int b    = line >> 9;
    const int p    = line & (SP - 1);          // h for axis 0, w for axis 1
    const int axis = dir >> 1;
    const int rev  = dir & 1;
    const float usub = (dir == 0) ? 0.0f : 1.0f;   // dirs 1-3 store L-u

    float Vc[DLBL];
#pragma unroll
    for (int j = 0; j < DLBL; ++j) Vc[j] = Vmat[j * DLBL + s];

    const float4* ub4 = (const float4*)((axis ? uT : unary)
                        + (long)(b * DLBL + s) * SPSP + (long)p * SP);
    // w stream: stride-1 everywhere (ewT overlay planes for vertical dirs)
    const float* wbase = axis
        ? ((dir == 2 ? l2t : l3t) + (long)(b * DLBL + 20) * SPSP + (long)p * SP)
        : (ew + (long)(b * 4 + dir) * SPSP + (long)p * SP);
    const float4* wb4 = (const float4*)wbase;

    const int frow = lane >> 5, fcol = lane & 31;
    const int stbase = s * 33;

    // flush per-task constants, hoisted out of the loop
    float* fb[3]; int wrev[3]; bool fvalid[3];
#pragma unroll
    for (int gg = 0; gg < 3; ++gg) {
        const int tid = blockIdx.x * 3 + gg;
        fvalid[gg] = (tid < 8192);
        int d_, ln;
        map_task(fvalid[gg] ? tid : 8191, d_, ln);
        const int bb = ln >> 9;
        const int pp = ln & (SP - 1);
        wrev[gg] = d_ & 1;
        float* dst = (d_ == 0) ? out : (d_ == 1) ? l1 : (d_ == 2) ? l2t : l3t;
        fb[gg] = dst + (long)(bb * DLBL) * SPSP + (long)pp * SP + (long)frow * SPSP;
    }

    float4 uS0[4], uS1[4], uS2[4], uS3[4];
    float4 wS0[4], wS1[4], wS2[4], wS3[4];
    float cur = 0.0f;

#define QIDX(bi, k) (rev ? (127 - 4 * (bi) - (k)) : (4 * (bi) + (k)))

// branchless clamped prefetch: blocks beyond 31 reload block 31 (values
// never consumed; addresses disjoint from all pending flush lines)
#define LOADB(bi_, U, W) do {                                               \
    const int bq_ = ((bi_) > 31) ? 31 : (bi_);                              \
    _Pragma("unroll")                                                       \
    for (int k = 0; k < 4; ++k) {                                           \
        const int q_ = QIDX(bq_, k);                                        \
        U[k] = ub4[q_]; W[k] = wb4[q_];                                     \
    } } while (0)

#define PROC(bi, U, W, FIRSTB) do {                                         \
    _Pragma("unroll")                                                       \
    for (int k = 0; k < 4; ++k) {                                           \
        const float ua_[4] = {U[k].x, U[k].y, U[k].z, U[k].w};              \
        const float wa_[4] = {W[k].x, W[k].y, W[k].z, W[k].w};              \
        const int q_ = QIDX(bi, k);                                         \
        _Pragma("unroll")                                                   \
        for (int j = 0; j < 4; ++j) {                                       \
            const int   jc  = rev ? 3 - j : j;                              \
            const float u_c = ua_[jc];                                      \
            const float w_c = wa_[jc];                                      \
            const int   t   = q_ * 4 + jc;                                  \
            xch[g][s] = cur;                                                \
            __builtin_amdgcn_wave_barrier();                                \
            float Lp[24];                                                   \
            _Pragma("unroll")                                               \
            for (int qq = 0; qq < 6; ++qq)                                  \
                ((float4*)Lp)[qq] = ((const float4*)(&xch[g][0]))[qq];      \
            __builtin_amdgcn_wave_barrier();                                \
            float c[DLBL];                                                  \
            _Pragma("unroll")                                               \
            for (int jj = 0; jj < DLBL; ++jj)                               \
                c[jj] = fmaf(w_c, Vc[jj], Lp[jj]);                          \
            float m7[7];                                                    \
            _Pragma("unroll")                                               \
            for (int kk = 0; kk < 7; ++kk)                                  \
                m7[kk] = fminf(fminf(c[3*kk], c[3*kk+1]), c[3*kk+2]);       \
            const float ma = fminf(fminf(m7[0], m7[1]), m7[2]);             \
            const float mb = fminf(fminf(m7[3], m7[4]), m7[5]);             \
            const float nv = u_c + fminf(fminf(ma, mb), m7[6]);             \
            cur = ((FIRSTB) && k == 0 && j == 0) ? u_c : nv;                \
            stage[g][stbase + (t & 31)] = fmaf(-usub, u_c, cur);            \
        }                                                                   \
    } } while (0)

#define FLW(w_) do {                                                        \
    __builtin_amdgcn_wave_barrier();                                        \
    _Pragma("unroll")                                                       \
    for (int gg = 0; gg < 3; ++gg) {                                        \
        if (fvalid[gg]) {                                                   \
            float* bp = fb[gg] + (wrev[gg] ? (480 - 32 * (w_))              \
                                           : (32 * (w_)));                  \
            _Pragma("unroll")                                               \
            for (int r2 = 0; r2 < 11; ++r2) {                               \
                const int rr = 2 * r2 + frow;                               \
                if (rr < DLBL) bp[fcol] = stage[gg][rr * 33 + fcol];        \
                bp += 2 * SPSP;                                             \
            }                                                               \
        }                                                                   \
    }                                                                       \
    __builtin_amdgcn_wave_barrier();                                        \
} while (0)

    LOADB(0, uS0, wS0);
    LOADB(1, uS1, wS1);
    LOADB(2, uS2, wS2);
    LOADB(3, uS3, wS3);

    for (int ww = 0; ww < 8; ++ww) {
        const int B0 = 4 * ww;
        PROC(B0 + 0, uS0, wS0, (ww == 0));
        LOADB(B0 + 4, uS0, wS0);
        PROC(B0 + 1, uS1, wS1, false);
        LOADB(B0 + 5, uS1, wS1);
        FLW(2 * ww);
        PROC(B0 + 2, uS2, wS2, false);
        LOADB(B0 + 6, uS2, wS2);
        PROC(B0 + 3, uS3, wS3, false);
        LOADB(B0 + 7, uS3, wS3);
        FLW(2 * ww + 1);
    }

#undef QIDX
#undef LOADB
#undef PROC
#undef FLW
}

// ---------------- finish: out += l1 + T(l2t) + T(l3t) ----------------
__global__ __launch_bounds__(256)
void finish_kernel(const float* __restrict__ l1, const float* __restrict__ l2t,
                   const float* __restrict__ l3t, float* __restrict__ out)
{
    __shared__ float t2[32][36], t3[32][36];
    const long pb = (long)blockIdx.z * SPSP;
    const int x0 = blockIdx.x * 32, y0 = blockIdx.y * 32;
    const int r  = threadIdx.x >> 3;           // 0..31
    const int c4 = (threadIdx.x & 7) * 4;      // 0,4,..,28
    const float4 v2 = *(const float4*)&l2t[pb + (long)(x0 + r) * SP + (y0 + c4)];
    const float4 v3 = *(const float4*)&l3t[pb + (long)(x0 + r) * SP + (y0 + c4)];
    *(float4*)&t2[r][c4] = v2;
    *(float4*)&t3[r][c4] = v3;
    __syncthreads();
    const long o = pb + (long)(y0 + r) * SP + (x0 + c4);
    const float4 a = *(const float4*)&l1[o];
    float4 ov = *(const float4*)&out[o];
    ov.x += a.x + t2[c4 + 0][r] + t3[c4 + 0][r];
    ov.y += a.y + t2[c4 + 1][r] + t3[c4 + 1][r];
    ov.z += a.z + t2[c4 + 2][r] + t3[c4 + 2][r];
    ov.w += a.w + t2[c4 + 3][r] + t3[c4 + 3][r];
    *(float4*)&out[o] = ov;
}

// ---------------- fallback (Path B): no-scratch sequential sweeps ----------
template<int MODE>   // 1: dir0 store L to out; 2: out += L - u
__global__ __launch_bounds__(64)
void sweep_fb(const float* __restrict__ unary, const float* __restrict__ ew,
              const float* __restrict__ Vmat, float* __restrict__ out,
              int taskBase)
{
    __shared__ float xch[4][24];
    const int lane = threadIdx.x;
    const int g    = lane / DLBL;
    const int s    = lane - g * DLBL;
    int local = blockIdx.x * 3 + (g < 3 ? g : 0);
    const bool valid = (g < 3) && (local < 2048);
    if (local >= 2048) local = 2047;
    const int taskId = taskBase + local;
    const int dir  = taskId >> 11;
    const int line = taskId & 2047;
    const int b = line >> 9, p = line & (SP - 1);
    const int axis = dir >> 1, rev = dir & 1;

    float Vc[DLBL];
#pragma unroll
    for (int j = 0; j < DLBL; ++j) Vc[j] = Vmat[j * DLBL + s];

    const long ustep = axis ? SP : 1;
    const long ubase = (long)(b * DLBL + s) * SPSP + (axis ? (long)p : (long)p * SP);
    const long wbase = (long)(b * 4 + dir) * SPSP + (axis ? (long)p : (long)p * SP);
    const long uoff  = rev ? -ustep : ustep;
    const long ust   = rev ? (long)(SP - 1) * ustep : 0;

    const float* up = unary + ubase + ust;
    const float* wp = ew    + wbase + ust;
    float*       op = out   + ubase + ust;

    float cur = up[0];
    if (valid && MODE == 1) *op = cur;

    float ub0 = up[uoff], ub1 = up[2*uoff], ub2 = up[3*uoff], ub3 = up[4*uoff];
    float wb0 = wp[uoff], wb1 = wp[2*uoff], wb2 = wp[3*uoff], wb3 = wp[4*uoff];
    float ob0 = 0, ob1 = 0, ob2 = 0, ob3 = 0;
    if (MODE == 2) { ob0 = op[uoff]; ob1 = op[2*uoff]; ob2 = op[3*uoff]; ob3 = op[4*uoff]; }
    const float* upf = up + 4 * uoff;
    const float* wpf = wp + 4 * uoff;
    const float* opf = op + 4 * uoff;

    for (int t = 1; t < SP; ++t) {
        const float u_c = ub0, w_c = wb0, o_c = ob0;
        ub0 = ub1; ub1 = ub2; ub2 = ub3;
        wb0 = wb1; wb1 = wb2; wb2 = wb3;
        if (MODE == 2) { ob0 = ob1; ob1 = ob2; ob2 = ob3; }
        const bool adv = (t + 4) < SP;
        upf += adv ? uoff : 0; wpf += adv ? uoff : 0;
        ub3 = *upf; wb3 = *wpf;
        if (MODE == 2) { opf += adv ? uoff : 0; ob3 = *opf; }

        xch[g][s] = cur;
        __builtin_amdgcn_wave_barrier();
        float Lp[24];
#pragma unroll
        for (int q = 0; q < 6; ++q)
            ((float4*)Lp)[q] = ((const float4*)(&xch[g][0]))[q];
        __builtin_amdgcn_wave_barrier();

        float c[DLBL];
#pragma unroll
        for (int j = 0; j < DLBL; ++j) c[j] = fmaf(w_c, Vc[j], Lp[j]);
        float m7[7];
#pragma unroll
        for (int k = 0; k < 7; ++k)
            m7[k] = fminf(fminf(c[3*k], c[3*k+1]), c[3*k+2]);
        const float ma = fminf(fminf(m7[0], m7[1]), m7[2]);
        const float mb = fminf(fminf(m7[3], m7[4]), m7[5]);
        cur = u_c + fminf(fminf(ma, mb), m7[6]);

        op += uoff;
        if (valid) *op = (MODE == 2) ? (o_c + cur - u_c) : cur;
    }
}

extern "C" void kernel_launch(void* const* d_in, const int* in_sizes, int n_in,
                              void* d_out, int out_size, void* d_ws, size_t ws_size,
                              hipStream_t stream) {
    const float* unary = (const float*)d_in[0];   // (4,1,21,512,512) f32
    const float* ew    = (const float*)d_in[1];   // (4,4,512,512)   f32
    const float* Vmat  = (const float*)d_in[2];   // (21,21)         f32
    float* o = (float*)d_out;

    const size_t needA = (size_t)(4 * NELEM) * sizeof(float);   // 352,321,536 B

    if (ws_size >= needA) {
        float* uT  = (float*)d_ws;
        float* l1  = uT + NELEM;
        float* l2t = l1 + NELEM;
        float* l3t = l2t + NELEM;

        dim3 tg(16, 16, NB * DLBL + 8);           // +8 ewT overlay planes
        transpose2_kernel<<<tg, 256, 0, stream>>>(unary, ew, uT, l2t, l3t);

        const int grid = (8192 + 2) / 3;          // 2731
        sweep5<<<grid, 64, 0, stream>>>(unary, ew, Vmat, uT,
                                        o, l1, l2t, l3t);

        finish_kernel<<<dim3(16, 16, NB * DLBL), 256, 0, stream>>>(l1, l2t, l3t, o);
    } else {
        const int grid = (2048 + 2) / 3;          // 683
        sweep_fb<1><<<grid, 64, 0, stream>>>(unary, ew, Vmat, o, 0);
        for (int d = 1; d < 4; ++d)
            sweep_fb<2><<<grid, 64, 0, stream>>>(unary, ew, Vmat, o, d * 2048);
    }
}

// Round 6
// 445.680 us; speedup vs baseline: 1.2452x; 1.0713x over previous
//
#include <hip/hip_runtime.h>

// SGM min-sum message passing, 4 directions, dense 21x21 label context.
// out = sum_d L_d - 3u.
//
// Path A (ws >= 4*NELEM floats exactly):
//   transpose2: uT[b][s][w][h] from u (84 planes) AND ewT planes for dirs
//     2,3 OVERLAID into l2t/l3t plane (b*21+20) -- no extra workspace.
//     float4 loads + [32][36] LDS tile.
//   sweep6: 8192 tasks, 21 lanes/task, 3 tasks/wave. R3's proven 2-slot
//     register pipeline (16-step blocks, conditional prefetch,
//     __launch_bounds__(64,3) -- ran at 3.2 TB/s effective) combined with
//     R5's direction-PAIRED task map (i<4096 -> dir=i&1,line=i>>1; else
//     dir=2+(j&1),line=j>>1) which cut FETCH to ~200 MB (fwd+bwd of a
//     line share u/uT lines in L2). R5's 4-slot/clamp/(64,2) structure is
//     REVERTED: it halved effective BW (2.2 TB/s), doubled LDS conflicts,
//     and blew the loop body to ~24KB.
//     Per-step all-to-all of 21 L values via padded LDS row (wave-sync).
//     Stores staged in LDS 32-step windows, flushed as full-line wave
//     stores: dir0->out (raw L), dir1->l1 (L-u), dir2/3->l2t/l3t (L-u,
//     transposed planes), all label-major. WRITE must be exactly 344064 KB.
//   finish: out += l1 + T(l2t) + T(l3t), float4 + [32][36] LDS tiles.
// Path B fallback (small ws): sequential no-scratch kernels (unchanged).

#define DLBL 21
#define SP 512
#define NB 4
#define SPSP ((long)SP * SP)
#define NELEM ((long)NB * DLBL * SP * SP)   // 22,020,096 floats

__device__ __forceinline__ void map_task(int i, int& dir, int& line)
{
    if (i < 4096) { dir = i & 1;       line = i >> 1; }
    else          { const int j = i - 4096; dir = 2 + (j & 1); line = j >> 1; }
}

// ---- transpose: u planes (0..83) + ewT overlay planes (84..91) ----
__global__ __launch_bounds__(256)
void transpose2_kernel(const float* __restrict__ u, const float* __restrict__ ew,
                       float* __restrict__ uT, float* l2t, float* l3t)
{
    __shared__ float tile[32][36];
    const int plane = blockIdx.z;
    const float* src;
    float* dst;
    if (plane < NB * DLBL) {
        src = u  + (long)plane * SPSP;
        dst = uT + (long)plane * SPSP;
    } else {
        const int q = plane - NB * DLBL;            // q = b*2 + (dir-2)
        const int b = q >> 1, db = q & 1;
        src = ew + (long)(b * 4 + 2 + db) * SPSP;
        dst = (db ? l3t : l2t) + (long)(b * DLBL + 20) * SPSP;  // overlay
    }
    const int x0 = blockIdx.x * 32, y0 = blockIdx.y * 32;
    const int r  = threadIdx.x >> 3;           // 0..31
    const int c4 = (threadIdx.x & 7) * 4;      // 0,4,..,28
    const float4 v = *(const float4*)&src[(long)(y0 + r) * SP + (x0 + c4)];
    *(float4*)&tile[r][c4] = v;
    __syncthreads();
    float4 ov;
    ov.x = tile[c4 + 0][r];
    ov.y = tile[c4 + 1][r];
    ov.z = tile[c4 + 2][r];
    ov.w = tile[c4 + 3][r];
    *(float4*)&dst[(long)(x0 + r) * SP + (y0 + c4)] = ov;
}

// ------------- main sweep (Path A, 2-slot pipeline + paired map) -----------
__global__ __launch_bounds__(64, 3)
void sweep6(const float* __restrict__ unary, const float* __restrict__ ew,
            const float* __restrict__ Vmat, const float* __restrict__ uT,
            float* __restrict__ out, float* __restrict__ l1,
            float* l2t, float* l3t)
{
    __shared__ float xch[4][24];
    __shared__ float stage[4][693];      // [group][s*33 + (t&31)], +1 pad/row
    const int lane = threadIdx.x;
    const int g    = lane / DLBL;              // 0..2 (3 = idle lane 63)
    const int s    = lane - g * DLBL;
    int taskId = blockIdx.x * 3 + (g < 3 ? g : 0);
    if (taskId >= 8192) taskId = 8191;

    int dir, line;
    map_task(taskId, dir, line);
    const int b    = line >> 9;
    const int p    = line & (SP - 1);          // h for axis 0, w for axis 1
    const int axis = dir >> 1;
    const int rev  = dir & 1;
    const float usub = (dir == 0) ? 0.0f : 1.0f;   // dirs 1-3 store L-u

    float Vc[DLBL];
#pragma unroll
    for (int j = 0; j < DLBL; ++j) Vc[j] = Vmat[j * DLBL + s];

    const float4* ub4 = (const float4*)((axis ? uT : unary)
                        + (long)(b * DLBL + s) * SPSP + (long)p * SP);
    // w stream: stride-1 everywhere (ewT overlay planes for vertical dirs)
    const float* wbase = axis
        ? ((dir == 2 ? l2t : l3t) + (long)(b * DLBL + 20) * SPSP + (long)p * SP)
        : (ew + (long)(b * 4 + dir) * SPSP + (long)p * SP);
    const float4* wb4 = (const float4*)wbase;

    const int frow = lane >> 5, fcol = lane & 31;
    const int stbase = s * 33;

    // flush per-task constants, hoisted out of the loop
    float* fb[3]; int wrev[3]; bool fvalid[3];
#pragma unroll
    for (int gg = 0; gg < 3; ++gg) {
        const int tid = blockIdx.x * 3 + gg;
        fvalid[gg] = (tid < 8192);
        int d_, ln;
        map_task(fvalid[gg] ? tid : 8191, d_, ln);
        const int bb = ln >> 9;
        const int pp = ln & (SP - 1);
        wrev[gg] = d_ & 1;
        float* dst = (d_ == 0) ? out : (d_ == 1) ? l1 : (d_ == 2) ? l2t : l3t;
        fb[gg] = dst + (long)(bb * DLBL) * SPSP + (long)pp * SP + (long)frow * SPSP;
    }

    float4 uA[4], uB[4], wA[4], wB[4];
    float cur = 0.0f;

#define QIDX(bi, k) (rev ? (127 - 4 * (bi) - (k)) : (4 * (bi) + (k)))

#define LOADBLK(bi, U, W) do {                                              \
    _Pragma("unroll")                                                       \
    for (int k = 0; k < 4; ++k) {                                           \
        const int q_ = QIDX(bi, k);                                         \
        U[k] = ub4[q_]; W[k] = wb4[q_];                                     \
    } } while (0)

#define PROC(bi, U, W, FIRSTB) do {                                         \
    _Pragma("unroll")                                                       \
    for (int k = 0; k < 4; ++k) {                                           \
        const float ua_[4] = {U[k].x, U[k].y, U[k].z, U[k].w};              \
        const float wa_[4] = {W[k].x, W[k].y, W[k].z, W[k].w};              \
        const int q_ = QIDX(bi, k);                                         \
        _Pragma("unroll")                                                   \
        for (int j = 0; j < 4; ++j) {                                       \
            const int   jc  = rev ? 3 - j : j;                              \
            const float u_c = ua_[jc];                                      \
            const float w_c = wa_[jc];                                      \
            const int   t   = q_ * 4 + jc;                                  \
            xch[g][s] = cur;                                                \
            __builtin_amdgcn_wave_barrier();                                \
            float Lp[24];                                                   \
            _Pragma("unroll")                                               \
            for (int qq = 0; qq < 6; ++qq)                                  \
                ((float4*)Lp)[qq] = ((const float4*)(&xch[g][0]))[qq];      \
            __builtin_amdgcn_wave_barrier();                                \
            float c[DLBL];                                                  \
            _Pragma("unroll")                                               \
            for (int jj = 0; jj < DLBL; ++jj)                               \
                c[jj] = fmaf(w_c, Vc[jj], Lp[jj]);                          \
            float m7[7];                                                    \
            _Pragma("unroll")                                               \
            for (int kk = 0; kk < 7; ++kk)                                  \
                m7[kk] = fminf(fminf(c[3*kk], c[3*kk+1]), c[3*kk+2]);       \
            const float ma = fminf(fminf(m7[0], m7[1]), m7[2]);             \
            const float mb = fminf(fminf(m7[3], m7[4]), m7[5]);             \
            const float nv = u_c + fminf(fminf(ma, mb), m7[6]);             \
            cur = ((FIRSTB) && k == 0 && j == 0) ? u_c : nv;                \
            stage[g][stbase + (t & 31)] = fmaf(-usub, u_c, cur);            \
        }                                                                   \
    } } while (0)

#define FLW(w_) do {                                                        \
    __builtin_amdgcn_wave_barrier();                                        \
    _Pragma("unroll")                                                       \
    for (int gg = 0; gg < 3; ++gg) {                                        \
        if (fvalid[gg]) {                                                   \
            float* bp = fb[gg] + (wrev[gg] ? (480 - 32 * (w_))              \
                                           : (32 * (w_)));                  \
            _Pragma("unroll")                                               \
            for (int r2 = 0; r2 < 11; ++r2) {                               \
                const int rr = 2 * r2 + frow;                               \
                if (rr < DLBL) bp[fcol] = stage[gg][rr * 33 + fcol];        \
                bp += 2 * SPSP;                                             \
            }                                                               \
        }                                                                   \
    }                                                                       \
    __builtin_amdgcn_wave_barrier();                                        \
} while (0)

    LOADBLK(0, uA, wA);
    for (int m = 0; m < 16; ++m) {
        LOADBLK(2 * m + 1, uB, wB);            // prefetch odd block
        PROC(2 * m, uA, wA, (m == 0));
        if (m < 15) LOADBLK(2 * m + 2, uA, wA);   // prefetch next even block
        PROC(2 * m + 1, uB, wB, false);
        FLW(m);                                // 32-step window complete
    }

#undef QIDX
#undef LOADBLK
#undef PROC
#undef FLW
}

// ---------------- finish: out += l1 + T(l2t) + T(l3t) ----------------
__global__ __launch_bounds__(256)
void finish_kernel(const float* __restrict__ l1, const float* __restrict__ l2t,
                   const float* __restrict__ l3t, float* __restrict__ out)
{
    __shared__ float t2[32][36], t3[32][36];
    const long pb = (long)blockIdx.z * SPSP;
    const int x0 = blockIdx.x * 32, y0 = blockIdx.y * 32;
    const int r  = threadIdx.x >> 3;           // 0..31
    const int c4 = (threadIdx.x & 7) * 4;      // 0,4,..,28
    const float4 v2 = *(const float4*)&l2t[pb + (long)(x0 + r) * SP + (y0 + c4)];
    const float4 v3 = *(const float4*)&l3t[pb + (long)(x0 + r) * SP + (y0 + c4)];
    *(float4*)&t2[r][c4] = v2;
    *(float4*)&t3[r][c4] = v3;
    __syncthreads();
    const long o = pb + (long)(y0 + r) * SP + (x0 + c4);
    const float4 a = *(const float4*)&l1[o];
    float4 ov = *(const float4*)&out[o];
    ov.x += a.x + t2[c4 + 0][r] + t3[c4 + 0][r];
    ov.y += a.y + t2[c4 + 1][r] + t3[c4 + 1][r];
    ov.z += a.z + t2[c4 + 2][r] + t3[c4 + 2][r];
    ov.w += a.w + t2[c4 + 3][r] + t3[c4 + 3][r];
    *(float4*)&out[o] = ov;
}

// ---------------- fallback (Path B): no-scratch sequential sweeps ----------
template<int MODE>   // 1: dir0 store L to out; 2: out += L - u
__global__ __launch_bounds__(64)
void sweep_fb(const float* __restrict__ unary, const float* __restrict__ ew,
              const float* __restrict__ Vmat, float* __restrict__ out,
              int taskBase)
{
    __shared__ float xch[4][24];
    const int lane = threadIdx.x;
    const int g    = lane / DLBL;
    const int s    = lane - g * DLBL;
    int local = blockIdx.x * 3 + (g < 3 ? g : 0);
    const bool valid = (g < 3) && (local < 2048);
    if (local >= 2048) local = 2047;
    const int taskId = taskBase + local;
    const int dir  = taskId >> 11;
    const int line = taskId & 2047;
    const int b = line >> 9, p = line & (SP - 1);
    const int axis = dir >> 1, rev = dir & 1;

    float Vc[DLBL];
#pragma unroll
    for (int j = 0; j < DLBL; ++j) Vc[j] = Vmat[j * DLBL + s];

    const long ustep = axis ? SP : 1;
    const long ubase = (long)(b * DLBL + s) * SPSP + (axis ? (long)p : (long)p * SP);
    const long wbase = (long)(b * 4 + dir) * SPSP + (axis ? (long)p : (long)p * SP);
    const long uoff  = rev ? -ustep : ustep;
    const long ust   = rev ? (long)(SP - 1) * ustep : 0;

    const float* up = unary + ubase + ust;
    const float* wp = ew    + wbase + ust;
    float*       op = out   + ubase + ust;

    float cur = up[0];
    if (valid && MODE == 1) *op = cur;

    float ub0 = up[uoff], ub1 = up[2*uoff], ub2 = up[3*uoff], ub3 = up[4*uoff];
    float wb0 = wp[uoff], wb1 = wp[2*uoff], wb2 = wp[3*uoff], wb3 = wp[4*uoff];
    float ob0 = 0, ob1 = 0, ob2 = 0, ob3 = 0;
    if (MODE == 2) { ob0 = op[uoff]; ob1 = op[2*uoff]; ob2 = op[3*uoff]; ob3 = op[4*uoff]; }
    const float* upf = up + 4 * uoff;
    const float* wpf = wp + 4 * uoff;
    const float* opf = op + 4 * uoff;

    for (int t = 1; t < SP; ++t) {
        const float u_c = ub0, w_c = wb0, o_c = ob0;
        ub0 = ub1; ub1 = ub2; ub2 = ub3;
        wb0 = wb1; wb1 = wb2; wb2 = wb3;
        if (MODE == 2) { ob0 = ob1; ob1 = ob2; ob2 = ob3; }
        const bool adv = (t + 4) < SP;
        upf += adv ? uoff : 0; wpf += adv ? uoff : 0;
        ub3 = *upf; wb3 = *wpf;
        if (MODE == 2) { opf += adv ? uoff : 0; ob3 = *opf; }

        xch[g][s] = cur;
        __builtin_amdgcn_wave_barrier();
        float Lp[24];
#pragma unroll
        for (int q = 0; q < 6; ++q)
            ((float4*)Lp)[q] = ((const float4*)(&xch[g][0]))[q];
        __builtin_amdgcn_wave_barrier();

        float c[DLBL];
#pragma unroll
        for (int j = 0; j < DLBL; ++j) c[j] = fmaf(w_c, Vc[j], Lp[j]);
        float m7[7];
#pragma unroll
        for (int k = 0; k < 7; ++k)
            m7[k] = fminf(fminf(c[3*k], c[3*k+1]), c[3*k+2]);
        const float ma = fminf(fminf(m7[0], m7[1]), m7[2]);
        const float mb = fminf(fminf(m7[3], m7[4]), m7[5]);
        cur = u_c + fminf(fminf(ma, mb), m7[6]);

        op += uoff;
        if (valid) *op = (MODE == 2) ? (o_c + cur - u_c) : cur;
    }
}

extern "C" void kernel_launch(void* const* d_in, const int* in_sizes, int n_in,
                              void* d_out, int out_size, void* d_ws, size_t ws_size,
                              hipStream_t stream) {
    const float* unary = (const float*)d_in[0];   // (4,1,21,512,512) f32
    const float* ew    = (const float*)d_in[1];   // (4,4,512,512)   f32
    const float* Vmat  = (const float*)d_in[2];   // (21,21)         f32
    float* o = (float*)d_out;

    const size_t needA = (size_t)(4 * NELEM) * sizeof(float);   // 352,321,536 B

    if (ws_size >= needA) {
        float* uT  = (float*)d_ws;
        float* l1  = uT + NELEM;
        float* l2t = l1 + NELEM;
        float* l3t = l2t + NELEM;

        dim3 tg(16, 16, NB * DLBL + 8);           // +8 ewT overlay planes
        transpose2_kernel<<<tg, 256, 0, stream>>>(unary, ew, uT, l2t, l3t);

        const int grid = (8192 + 2) / 3;          // 2731
        sweep6<<<grid, 64, 0, stream>>>(unary, ew, Vmat, uT,
                                        o, l1, l2t, l3t);

        finish_kernel<<<dim3(16, 16, NB * DLBL), 256, 0, stream>>>(l1, l2t, l3t, o);
    } else {
        const int grid = (2048 + 2) / 3;          // 683
        sweep_fb<1><<<grid, 64, 0, stream>>>(unary, ew, Vmat, o, 0);
        for (int d = 1; d < 4; ++d)
            sweep_fb<2><<<grid, 64, 0, stream>>>(unary, ew, Vmat, o, d * 2048);
    }
}